// Round 2
// baseline (38.338 us; speedup 1.0000x reference)
//
#include <hip/hip_runtime.h>
#include <math.h>

#define NROWS   8192
#define KP1     17
#define ROWS_PER_BLOCK 8
#define NBLOCKS (NROWS / ROWS_PER_BLOCK)   // 1024 blocks x 256 threads

// d_ws layout:
//   [0]            : unsigned int counter   (memset to 0 each launch)
//   [256]          : float expv[8192]
//   [256 + 32768]  : float partial[1024]

__global__ __launch_bounds__(256) void fused_gather_softmax(
    const float* __restrict__ data,
    const int*   __restrict__ nidx,
    float*       __restrict__ alpha,
    float*       __restrict__ a_raw,
    float*       __restrict__ expv,
    float*       __restrict__ partial,
    unsigned int* __restrict__ counter)
{
    __shared__ float lds_exp[ROWS_PER_BLOCK];
    __shared__ float red[4];
    __shared__ int   lastf;

    const int t        = threadIdx.x;
    const int rowLocal = t >> 5;            // 32 lanes per row
    const int lane     = t & 31;
    const int row      = blockIdx.x * ROWS_PER_BLOCK + rowLocal;

    // ---- Phase 1: gather + row sum ----
    float v = 0.0f;
    if (lane < KP1) {
        int c = nidx[row * KP1 + lane];
        v = data[(size_t)row * NROWS + (size_t)c];
    }
    #pragma unroll
    for (int off = 16; off > 0; off >>= 1)
        v += __shfl_down(v, off, 32);

    if (lane == 0) {
        a_raw[row] = v;
        float ev = expf(v);     // no max-subtraction: |v| <= ~25, safe in f32
        expv[row] = ev;
        lds_exp[rowLocal] = ev;
    }
    __syncthreads();            // drains vmem: all global writes in L2

    // ---- per-block partial exp-sum, release, arrive ----
    if (t == 0) {
        float s = 0.0f;
        #pragma unroll
        for (int i = 0; i < ROWS_PER_BLOCK; ++i) s += lds_exp[i];
        partial[blockIdx.x] = s;
        __threadfence();        // agent release: writeback L2 (covers whole block's writes)
        unsigned int old = atomicAdd(counter, 1u);
        lastf = (old == NBLOCKS - 1) ? 1 : 0;
    }
    __syncthreads();
    if (!lastf) return;

    // ---- Phase 2 (last block only): reduce partials, normalize ----
    __threadfence();            // agent acquire: invalidate L1/L2 so reads are fresh

    float s = 0.0f;
    #pragma unroll
    for (int i = 0; i < 4; ++i)
        s += partial[t + i * 256];          // fixed order: deterministic
    #pragma unroll
    for (int off = 32; off > 0; off >>= 1)
        s += __shfl_down(s, off, 64);
    if ((t & 63) == 0) red[t >> 6] = s;
    __syncthreads();
    if (t == 0) red[0] = (red[0] + red[1]) + (red[2] + red[3]);
    __syncthreads();
    const float inv = 1.0f / red[0];

    const float4* e4 = (const float4*)expv;
    float4*       a4 = (float4*)alpha;
    #pragma unroll
    for (int i = t; i < NROWS / 4; i += 256) {
        float4 x = e4[i];
        x.x *= inv; x.y *= inv; x.z *= inv; x.w *= inv;
        a4[i] = x;
    }
}

extern "C" void kernel_launch(void* const* d_in, const int* in_sizes, int n_in,
                              void* d_out, int out_size, void* d_ws, size_t ws_size,
                              hipStream_t stream) {
    const float* data = (const float*)d_in[0];
    const int*   nidx = (const int*)d_in[1];
    float* alpha = (float*)d_out;            // output 0: alpha (8192)
    float* a_raw = (float*)d_out + NROWS;    // output 1: A_raw (8192)

    unsigned int* counter = (unsigned int*)d_ws;
    float* expv    = (float*)((char*)d_ws + 256);
    float* partial = (float*)((char*)d_ws + 256 + NROWS * sizeof(float));

    hipMemsetAsync(counter, 0, sizeof(unsigned int), stream);
    fused_gather_softmax<<<NBLOCKS, 256, 0, stream>>>(
        data, nidx, alpha, a_raw, expv, partial, counter);
}

// Round 3
// 21.043 us; speedup vs baseline: 1.8219x; 1.8219x over previous
//
#include <hip/hip_runtime.h>
#include <math.h>

#define NROWS 8192
#define KP1   17
#define RPB   32                 // rows per block
#define NBLK  (NROWS / RPB)      // 256 blocks x 1024 threads
#define FXSCALE 1048576.0        // 2^20 fixed-point scale for deterministic sum

// d_ws layout: [0..7] u64 gsum, [8..11] u32 counter  (memset to 0 each launch)

__global__ __launch_bounds__(1024) void fused_gather_softmax(
    const float* __restrict__ data,
    const int*   __restrict__ nidx,
    float* __restrict__ alpha,
    float* __restrict__ a_raw,
    unsigned long long* __restrict__ gsum,
    unsigned int* __restrict__ counter)
{
    __shared__ float lds_exp[RPB];
    __shared__ float s_inv;

    const int t        = threadIdx.x;
    const int rowLocal = t >> 5;            // 32 lanes per row
    const int lane     = t & 31;
    const int row      = blockIdx.x * RPB + rowLocal;

    // ---- Phase 1: gather + row sum ----
    float v = 0.0f;
    if (lane < KP1) {
        int c = nidx[row * KP1 + lane];
        v = data[(size_t)row * NROWS + (size_t)c];
    }
    #pragma unroll
    for (int off = 16; off > 0; off >>= 1)
        v += __shfl_down(v, off, 32);

    float ev = 0.0f;
    if (lane == 0) {
        a_raw[row] = v;
        ev = expf(v);            // no max-subtraction: |v| <= ~25, safe in f32
        lds_exp[rowLocal] = ev;  // block-local only
    }
    __syncthreads();

    // ---- join: one fixed-point atomic per block, then spin on counter ----
    if (t == 0) {
        float p = 0.0f;
        #pragma unroll
        for (int i = 0; i < RPB; ++i) p += lds_exp[i];
        unsigned long long fx =
            (unsigned long long)((double)p * FXSCALE + 0.5);
        unsigned long long old = atomicAdd(gsum, fx);     // device-scope, coherent
        asm volatile("" :: "v"(old));   // data-dep: gsum add completes before counter bump
        atomicAdd(counter, 1u);

        while (__hip_atomic_load(counter, __ATOMIC_RELAXED,
                                 __HIP_MEMORY_SCOPE_AGENT) < NBLK)
            __builtin_amdgcn_s_sleep(2);

        unsigned long long tot = __hip_atomic_load(
            gsum, __ATOMIC_RELAXED, __HIP_MEMORY_SCOPE_AGENT);
        s_inv = (float)(FXSCALE / (double)tot);
    }
    __syncthreads();

    // ---- Phase 2: each block normalizes its own rows (register-held exp) ----
    if (lane == 0)
        alpha[row] = ev * s_inv;
}

extern "C" void kernel_launch(void* const* d_in, const int* in_sizes, int n_in,
                              void* d_out, int out_size, void* d_ws, size_t ws_size,
                              hipStream_t stream) {
    const float* data = (const float*)d_in[0];
    const int*   nidx = (const int*)d_in[1];
    float* alpha = (float*)d_out;            // output 0: alpha (8192)
    float* a_raw = (float*)d_out + NROWS;    // output 1: A_raw (8192)

    unsigned long long* gsum    = (unsigned long long*)d_ws;
    unsigned int*       counter = (unsigned int*)((char*)d_ws + 8);

    hipMemsetAsync(d_ws, 0, 16, stream);
    fused_gather_softmax<<<NBLK, 1024, 0, stream>>>(
        data, nidx, alpha, a_raw, gsum, counter);
}

// Round 4
// 12.681 us; speedup vs baseline: 3.0233x; 1.6594x over previous
//
#include <hip/hip_runtime.h>
#include <math.h>

#define NROWS 8192
#define KP1   17

// ---- Kernel A: one 32-lane group per row; lanes 0..16 gather; lane 0 writes A_raw.
__global__ __launch_bounds__(256) void gather_sum_kernel(
    const float* __restrict__ data,
    const int* __restrict__ nidx,
    float* __restrict__ a_raw)
{
    int tid  = blockIdx.x * blockDim.x + threadIdx.x;
    int row  = tid >> 5;
    int lane = tid & 31;

    float v = 0.0f;
    if (lane < KP1) {
        int c = nidx[row * KP1 + lane];
        v = data[(size_t)row * NROWS + (size_t)c];
    }
    #pragma unroll
    for (int off = 16; off > 0; off >>= 1)
        v += __shfl_down(v, off, 32);

    if (lane == 0) a_raw[row] = v;
}

// ---- Kernel B: 8 blocks x 1024 threads. Each block redundantly computes the
// full exp-sum over all 8192 values (L2-resident, 32 KB), then normalizes its
// own 1024-element slice. No cross-block communication, fixed reduction tree.
__global__ __launch_bounds__(1024) void softmax_norm_kernel(
    const float* __restrict__ a_raw,
    float* __restrict__ alpha)
{
    __shared__ float red[16];
    const int t    = threadIdx.x;
    const int wave = t >> 6;
    const int lane = t & 63;

    float vals[8];
    float s = 0.0f;
    #pragma unroll
    for (int i = 0; i < 8; ++i) {
        vals[i] = expf(a_raw[t + i * 1024]);   // no max-subtraction: |A_raw|<=~25
        s += vals[i];
    }
    #pragma unroll
    for (int off = 32; off > 0; off >>= 1)
        s += __shfl_down(s, off, 64);
    if (lane == 0) red[wave] = s;
    __syncthreads();
    if (wave == 0) {
        float ss = (lane < 16) ? red[lane] : 0.0f;
        #pragma unroll
        for (int off = 8; off > 0; off >>= 1)
            ss += __shfl_down(ss, off, 64);
        if (lane == 0) red[0] = ss;
    }
    __syncthreads();
    const float inv = 1.0f / red[0];

    // my slice's value is vals[blockIdx.x]; select with compile-time indices
    // (runtime-indexed register arrays spill to scratch — rule #20)
    float mine = vals[0];
    #pragma unroll
    for (int i = 1; i < 8; ++i)
        if ((int)blockIdx.x == i) mine = vals[i];

    alpha[blockIdx.x * 1024 + t] = mine * inv;
}

extern "C" void kernel_launch(void* const* d_in, const int* in_sizes, int n_in,
                              void* d_out, int out_size, void* d_ws, size_t ws_size,
                              hipStream_t stream) {
    const float* data = (const float*)d_in[0];
    const int*   nidx = (const int*)d_in[1];
    float* alpha = (float*)d_out;            // output 0: alpha (8192)
    float* a_raw = (float*)d_out + NROWS;    // output 1: A_raw (8192)

    gather_sum_kernel<<<(NROWS * 32) / 256, 256, 0, stream>>>(data, nidx, a_raw);
    softmax_norm_kernel<<<8, 1024, 0, stream>>>(a_raw, alpha);
}

// Round 5
// 12.647 us; speedup vs baseline: 3.0313x; 1.0027x over previous
//
#include <hip/hip_runtime.h>
#include <math.h>

#define NROWS 8192
#define KP1   17

// ---- Kernel A: 16 lanes per row. Lane k loads idx[k]+gather; idx[16]'s
// gather is loaded wave-uniform (same-address broadcast, 1 line request)
// and added at lane 0 only. 256 blocks x 512 threads = 1 block/CU, 8 waves.
__global__ __launch_bounds__(512) void gather_sum_kernel(
    const float* __restrict__ data,
    const int* __restrict__ nidx,
    float* __restrict__ a_raw)
{
    int tid = blockIdx.x * 512 + threadIdx.x;
    int row = tid >> 4;
    int k   = tid & 15;

    const int* ip = nidx + row * KP1;
    int c0  = ip[k];        // per-lane index
    int c16 = ip[16];       // wave-uniform per 16-lane group (broadcast line)

    const float* rp = data + (size_t)row * NROWS;
    float v   = rp[c0];
    float v16 = rp[c16];    // same address across the 16-lane group: 1 request

    v += (k == 0) ? v16 : 0.0f;

    #pragma unroll
    for (int off = 8; off > 0; off >>= 1)
        v += __shfl_down(v, off, 16);

    if (k == 0) a_raw[row] = v;
}

// ---- Kernel B: 8 blocks x 1024 threads. Each block redundantly computes the
// full exp-sum over all 8192 values (L2-resident, 32 KB), then normalizes its
// own 1024-element slice. No cross-block communication, fixed reduction tree.
__global__ __launch_bounds__(1024) void softmax_norm_kernel(
    const float* __restrict__ a_raw,
    float* __restrict__ alpha)
{
    __shared__ float red[16];
    const int t    = threadIdx.x;
    const int wave = t >> 6;
    const int lane = t & 63;

    float vals[8];
    float s = 0.0f;
    #pragma unroll
    for (int i = 0; i < 8; ++i) {
        vals[i] = expf(a_raw[t + i * 1024]);   // no max-subtraction: |A_raw|<=~25
        s += vals[i];
    }
    #pragma unroll
    for (int off = 32; off > 0; off >>= 1)
        s += __shfl_down(s, off, 64);
    if (lane == 0) red[wave] = s;
    __syncthreads();
    if (wave == 0) {
        float ss = (lane < 16) ? red[lane] : 0.0f;
        #pragma unroll
        for (int off = 8; off > 0; off >>= 1)
            ss += __shfl_down(ss, off, 64);
        if (lane == 0) red[0] = ss;
    }
    __syncthreads();
    const float inv = 1.0f / red[0];

    // my slice's value is vals[blockIdx.x]; select with compile-time indices
    // (runtime-indexed register arrays spill to scratch — rule #20)
    float mine = vals[0];
    #pragma unroll
    for (int i = 1; i < 8; ++i)
        if ((int)blockIdx.x == i) mine = vals[i];

    alpha[blockIdx.x * 1024 + t] = mine * inv;
}

extern "C" void kernel_launch(void* const* d_in, const int* in_sizes, int n_in,
                              void* d_out, int out_size, void* d_ws, size_t ws_size,
                              hipStream_t stream) {
    const float* data = (const float*)d_in[0];
    const int*   nidx = (const int*)d_in[1];
    float* alpha = (float*)d_out;            // output 0: alpha (8192)
    float* a_raw = (float*)d_out + NROWS;    // output 1: A_raw (8192)

    gather_sum_kernel<<<(NROWS * 16) / 512, 512, 0, stream>>>(data, nidx, a_raw);
    softmax_norm_kernel<<<8, 1024, 0, stream>>>(a_raw, alpha);
}

// Round 6
// 11.308 us; speedup vs baseline: 3.3903x; 1.1184x over previous
//
#include <hip/hip_runtime.h>
#include <math.h>

#define NROWS 8192
#define KP1   17
#define RPB_A 32    // rows per block in kernel A (512 threads / 16 lanes)

// ---- Kernel A: 16 lanes per row; also produces per-block partial exp-sums.
// 256 blocks x 512 threads. Lane k gathers idx[k]; idx[16] is wave-uniform
// per 16-lane group (broadcast line) and added at lane 0.
__global__ __launch_bounds__(512) void gather_sum_kernel(
    const float* __restrict__ data,
    const int* __restrict__ nidx,
    float* __restrict__ a_raw,
    float* __restrict__ partial)
{
    __shared__ float lds_exp[RPB_A];

    const int t   = threadIdx.x;
    int tid = blockIdx.x * 512 + t;
    int row = tid >> 4;
    int k   = tid & 15;

    const int* ip = nidx + row * KP1;
    int c0  = ip[k];        // per-lane index
    int c16 = ip[16];       // uniform per 16-lane group: broadcast line

    const float* rp = data + (size_t)row * NROWS;
    float v   = rp[c0];
    float v16 = rp[c16];

    v += (k == 0) ? v16 : 0.0f;

    #pragma unroll
    for (int off = 8; off > 0; off >>= 1)
        v += __shfl_down(v, off, 16);

    if (k == 0) {
        a_raw[row] = v;
        lds_exp[t >> 4] = expf(v);   // no max-subtraction: |A_raw| <= ~25
    }
    __syncthreads();

    // block partial: fixed shuffle tree over 32 row-exps (deterministic)
    if (t < 32) {
        float p = lds_exp[t];
        #pragma unroll
        for (int off = 16; off > 0; off >>= 1)
            p += __shfl_down(p, off, 32);
        if (t == 0) partial[blockIdx.x] = p;
    }
}

// ---- Kernel B: 32 blocks x 256 threads. Each block reduces the 256 partials
// (1 KB, L2-hit, fixed tree) and normalizes its own 256-row slice.
__global__ __launch_bounds__(256) void softmax_norm_kernel(
    const float* __restrict__ a_raw,
    const float* __restrict__ partial,
    float* __restrict__ alpha)
{
    __shared__ float red[4];
    const int t    = threadIdx.x;
    const int wave = t >> 6;
    const int lane = t & 63;
    const int row  = blockIdx.x * 256 + t;

    float e = expf(a_raw[row]);      // start the dependent chain early

    float s = partial[t];
    #pragma unroll
    for (int off = 32; off > 0; off >>= 1)
        s += __shfl_down(s, off, 64);
    if (lane == 0) red[wave] = s;
    __syncthreads();
    if (t == 0) red[0] = (red[0] + red[1]) + (red[2] + red[3]);
    __syncthreads();

    alpha[row] = e * (1.0f / red[0]);
}

extern "C" void kernel_launch(void* const* d_in, const int* in_sizes, int n_in,
                              void* d_out, int out_size, void* d_ws, size_t ws_size,
                              hipStream_t stream) {
    const float* data = (const float*)d_in[0];
    const int*   nidx = (const int*)d_in[1];
    float* alpha   = (float*)d_out;            // output 0: alpha (8192)
    float* a_raw   = (float*)d_out + NROWS;    // output 1: A_raw (8192)
    float* partial = (float*)d_ws;             // 256 floats

    gather_sum_kernel<<<(NROWS * 16) / 512, 512, 0, stream>>>(data, nidx, a_raw, partial);
    softmax_norm_kernel<<<32, 256, 0, stream>>>(a_raw, partial, alpha);
}